// Round 1
// baseline (381.493 us; speedup 1.0000x reference)
//
#include <hip/hip_runtime.h>

typedef unsigned short u16;
typedef u16 u16x8 __attribute__((ext_vector_type(8)));
typedef __bf16 bf16x8 __attribute__((ext_vector_type(8)));
typedef float f32x4 __attribute__((ext_vector_type(4)));

__device__ __forceinline__ u16 f2bf(float f) {
  unsigned int u = __float_as_uint(f);
  u += 0x7fffu + ((u >> 16) & 1u);
  return (u16)(u >> 16);
}

__device__ __forceinline__ f32x4 mfma16(bf16x8 a, bf16x8 b, f32x4 c) {
  return __builtin_amdgcn_mfma_f32_16x16x32_bf16(a, b, c, 0, 0, 0);
}

// ---------------- fp32 -> bf16 convert (x) ----------------
__global__ __launch_bounds__(256) void cvt_x(const float* __restrict__ in,
                                             u16* __restrict__ out, int n) {
  int i = (blockIdx.x * 256 + threadIdx.x) * 8;
  if (i >= n) return;
  u16x8 o;
#pragma unroll
  for (int j = 0; j < 8; j++) o[j] = f2bf(in[i + j]);
  *(u16x8*)&out[i] = o;
}

// ------------- transpose + convert: in [R][C] f32 -> out [C][R] bf16 -------------
__global__ __launch_bounds__(256) void transpose_cvt(const float* __restrict__ in,
                                                     u16* __restrict__ out,
                                                     int R, int C) {
  __shared__ float tile[32][33];
  int gx = blockIdx.x * 32, gy = blockIdx.y * 32;
  int tx = threadIdx.x, ty = threadIdx.y;
#pragma unroll
  for (int i = 0; i < 4; i++)
    tile[ty + i * 8][tx] = in[(size_t)(gy + ty + i * 8) * C + gx + tx];
  __syncthreads();
#pragma unroll
  for (int i = 0; i < 4; i++) {
    int c = ty + i * 8;
    out[(size_t)(gx + c) * R + gy + tx] = f2bf(tile[tx][c]);
  }
}

// ---------------- GEMM: C[M,N] = A[M,K] * Bt[N,K]^T  (bf16 in, fp32 acc) ----------
// EPI 0: QKV epilogue -> scatter to q (x0.125), k, v^T buffers (bf16)
// EPI 1: fp32 out + bias
template <int EPI>
__global__ __launch_bounds__(256, 2) void gemm_bf16(
    const u16* __restrict__ A, const u16* __restrict__ Bt,
    const float* __restrict__ bias, u16* __restrict__ qb, u16* __restrict__ kb,
    u16* __restrict__ vb, float* __restrict__ fout, int N, int K) {
  __shared__ u16 As[128][40];
  __shared__ u16 Bs[128][40];
  const int tid = threadIdx.x;
  const int wave = tid >> 6;
  const int lane = tid & 63;
  const int wr = wave >> 1, wc = wave & 1;
  const int l15 = lane & 15, l4 = lane >> 4;
  const int bm = blockIdx.y * 128, bn = blockIdx.x * 128;
  const int srow = tid >> 2;
  const int scol = (tid & 3) * 8;

  const u16* Ap = A + (size_t)(bm + srow) * K + scol;
  const u16* Bp = Bt + (size_t)(bn + srow) * K + scol;
  const size_t rstep = (size_t)64 * K;

  f32x4 acc[4][4] = {};

  u16x8 ra0 = *(const u16x8*)(Ap);
  u16x8 ra1 = *(const u16x8*)(Ap + rstep);
  u16x8 rb0 = *(const u16x8*)(Bp);
  u16x8 rb1 = *(const u16x8*)(Bp + rstep);

  for (int k0 = 0; k0 < K; k0 += 32) {
    __syncthreads();
    *(u16x8*)&As[srow][scol] = ra0;
    *(u16x8*)&As[srow + 64][scol] = ra1;
    *(u16x8*)&Bs[srow][scol] = rb0;
    *(u16x8*)&Bs[srow + 64][scol] = rb1;
    __syncthreads();
    if (k0 + 32 < K) {
      ra0 = *(const u16x8*)(Ap + k0 + 32);
      ra1 = *(const u16x8*)(Ap + rstep + k0 + 32);
      rb0 = *(const u16x8*)(Bp + k0 + 32);
      rb1 = *(const u16x8*)(Bp + rstep + k0 + 32);
    }
    bf16x8 af[4], bfr[4];
#pragma unroll
    for (int mi = 0; mi < 4; mi++)
      af[mi] = *(const bf16x8*)&As[wr * 64 + mi * 16 + l15][l4 * 8];
#pragma unroll
    for (int ni = 0; ni < 4; ni++)
      bfr[ni] = *(const bf16x8*)&Bs[wc * 64 + ni * 16 + l15][l4 * 8];
#pragma unroll
    for (int mi = 0; mi < 4; mi++)
#pragma unroll
      for (int ni = 0; ni < 4; ni++)
        acc[mi][ni] = mfma16(af[mi], bfr[ni], acc[mi][ni]);
  }

#pragma unroll
  for (int mi = 0; mi < 4; mi++) {
#pragma unroll
    for (int ni = 0; ni < 4; ni++) {
      const int col = bn + wc * 64 + ni * 16 + l15;
      const float bv = bias[col];
      const int row0 = bm + wr * 64 + mi * 16 + l4 * 4;
      if (EPI == 0) {
        const int which = col >> 10;
        const int hc = col & 1023;
        const int h = hc >> 6, d = hc & 63;
#pragma unroll
        for (int r = 0; r < 4; r++) {
          const int row = row0 + r;
          const int b = row >> 11, t = row & 2047;
          const float v = acc[mi][ni][r] + bv;
          if (which == 0)
            qb[((size_t)(b * 16 + h) * 2048 + t) * 64 + d] = f2bf(v * 0.125f);
          else if (which == 1)
            kb[((size_t)(b * 16 + h) * 2048 + t) * 64 + d] = f2bf(v);
          else
            vb[((size_t)(b * 16 + h) * 64 + d) * 2048 + t] = f2bf(v);
        }
      } else {
#pragma unroll
        for (int r = 0; r < 4; r++)
          fout[(size_t)(row0 + r) * N + col] = acc[mi][ni][r] + bv;
      }
    }
  }
}

// ---------------- flash attention ----------------
// Q,K: [64 bh][2048][64] bf16 (Q pre-scaled by 0.125); Vt: [64 bh][64][2048] bf16
// O: [4 b][2048 t][1024] bf16
__global__ __launch_bounds__(256, 2) void attn_kernel(const u16* __restrict__ Q,
                                                      const u16* __restrict__ Kg,
                                                      const u16* __restrict__ Vt,
                                                      u16* __restrict__ O) {
  __shared__ u16 Qs[128 * 64];
  __shared__ u16 Ks[64 * 72];
  __shared__ u16 Vs[64 * 72];
  __shared__ u16 Ps[4][32 * 72];
  const int tid = threadIdx.x;
  const int wave = tid >> 6;
  const int lane = tid & 63;
  const int l15 = lane & 15, l4 = lane >> 4;
  const int qt = blockIdx.x;
  const int bh = blockIdx.y;

  const u16* qg = Q + ((size_t)bh * 2048 + qt * 128) * 64;
#pragma unroll
  for (int i = 0; i < 4; i++)
    *(u16x8*)&Qs[i * 2048 + tid * 8] = *(const u16x8*)&qg[i * 2048 + tid * 8];
  __syncthreads();

  bf16x8 qf[2][2];
#pragma unroll
  for (int mi = 0; mi < 2; mi++)
#pragma unroll
    for (int kg2 = 0; kg2 < 2; kg2++)
      qf[mi][kg2] =
          *(const bf16x8*)&Qs[(wave * 32 + mi * 16 + l15) * 64 + kg2 * 32 + l4 * 8];

  float mrow[2][4], lrow[2][4];
#pragma unroll
  for (int mi = 0; mi < 2; mi++)
#pragma unroll
    for (int r = 0; r < 4; r++) {
      mrow[mi][r] = -1e30f;
      lrow[mi][r] = 0.f;
    }
  f32x4 oacc[2][4] = {};

  const int sr = tid >> 2;
  const int sc = (tid & 3) * 16;
  const u16* kbase = Kg + (size_t)bh * 2048 * 64;
  const u16* vbase = Vt + (size_t)bh * 64 * 2048;

  for (int kt = 0; kt < 32; kt++) {
    __syncthreads();
    {
      u16x8 k0v = *(const u16x8*)(kbase + (size_t)(kt * 64 + sr) * 64 + sc);
      u16x8 k1v = *(const u16x8*)(kbase + (size_t)(kt * 64 + sr) * 64 + sc + 8);
      u16x8 v0v = *(const u16x8*)(vbase + (size_t)sr * 2048 + kt * 64 + sc);
      u16x8 v1v = *(const u16x8*)(vbase + (size_t)sr * 2048 + kt * 64 + sc + 8);
      *(u16x8*)&Ks[sr * 72 + sc] = k0v;
      *(u16x8*)&Ks[sr * 72 + sc + 8] = k1v;
      *(u16x8*)&Vs[sr * 72 + sc] = v0v;
      *(u16x8*)&Vs[sr * 72 + sc + 8] = v1v;
    }
    __syncthreads();

    f32x4 sacc[2][4] = {};
#pragma unroll
    for (int kg2 = 0; kg2 < 2; kg2++) {
#pragma unroll
      for (int ni = 0; ni < 4; ni++) {
        bf16x8 kf = *(const bf16x8*)&Ks[(ni * 16 + l15) * 72 + kg2 * 32 + l4 * 8];
#pragma unroll
        for (int mi = 0; mi < 2; mi++)
          sacc[mi][ni] = mfma16(qf[mi][kg2], kf, sacc[mi][ni]);
      }
    }

#pragma unroll
    for (int mi = 0; mi < 2; mi++) {
#pragma unroll
      for (int r = 0; r < 4; r++) {
        float mx = fmaxf(fmaxf(sacc[mi][0][r], sacc[mi][1][r]),
                         fmaxf(sacc[mi][2][r], sacc[mi][3][r]));
        mx = fmaxf(mx, __shfl_xor(mx, 1));
        mx = fmaxf(mx, __shfl_xor(mx, 2));
        mx = fmaxf(mx, __shfl_xor(mx, 4));
        mx = fmaxf(mx, __shfl_xor(mx, 8));
        const float mold = mrow[mi][r];
        const float mnew = fmaxf(mold, mx);
        const float alpha = exp2f((mold - mnew) * 1.44269504f);
        mrow[mi][r] = mnew;
        float rsum = 0.f;
#pragma unroll
        for (int ni = 0; ni < 4; ni++) {
          float p = exp2f((sacc[mi][ni][r] - mnew) * 1.44269504f);
          sacc[mi][ni][r] = p;
          rsum += p;
        }
        rsum += __shfl_xor(rsum, 1);
        rsum += __shfl_xor(rsum, 2);
        rsum += __shfl_xor(rsum, 4);
        rsum += __shfl_xor(rsum, 8);
        lrow[mi][r] = lrow[mi][r] * alpha + rsum;
#pragma unroll
        for (int di = 0; di < 4; di++) oacc[mi][di][r] *= alpha;
      }
    }

#pragma unroll
    for (int mi = 0; mi < 2; mi++)
#pragma unroll
      for (int ni = 0; ni < 4; ni++)
#pragma unroll
        for (int r = 0; r < 4; r++)
          Ps[wave][(mi * 16 + l4 * 4 + r) * 72 + ni * 16 + l15] =
              f2bf(sacc[mi][ni][r]);
    __syncthreads();  // orders u16 P-writes vs vector P-reads (aliasing safety)

#pragma unroll
    for (int kg2 = 0; kg2 < 2; kg2++) {
      bf16x8 pf[2];
#pragma unroll
      for (int mi = 0; mi < 2; mi++)
        pf[mi] = *(const bf16x8*)&Ps[wave][(mi * 16 + l15) * 72 + kg2 * 32 + l4 * 8];
#pragma unroll
      for (int di = 0; di < 4; di++) {
        bf16x8 vf = *(const bf16x8*)&Vs[(di * 16 + l15) * 72 + kg2 * 32 + l4 * 8];
#pragma unroll
        for (int mi = 0; mi < 2; mi++)
          oacc[mi][di] = mfma16(pf[mi], vf, oacc[mi][di]);
      }
    }
  }

  const int b = bh >> 4, h = bh & 15;
#pragma unroll
  for (int mi = 0; mi < 2; mi++) {
    float inv[4];
#pragma unroll
    for (int r = 0; r < 4; r++) inv[r] = 1.0f / lrow[mi][r];
#pragma unroll
    for (int di = 0; di < 4; di++) {
#pragma unroll
      for (int r = 0; r < 4; r++) {
        const int t = qt * 128 + wave * 32 + mi * 16 + l4 * 4 + r;
        const int col = h * 64 + di * 16 + l15;
        O[((size_t)b * 2048 + t) * 1024 + col] = f2bf(oacc[mi][di][r] * inv[r]);
      }
    }
  }
}

extern "C" void kernel_launch(void* const* d_in, const int* in_sizes, int n_in,
                              void* d_out, int out_size, void* d_ws, size_t ws_size,
                              hipStream_t stream) {
  const float* x = (const float*)d_in[0];
  const float* Wqkv = (const float*)d_in[1];
  const float* bqkv = (const float*)d_in[2];
  const float* Wout = (const float*)d_in[3];
  const float* bout = (const float*)d_in[4];
  float* out = (float*)d_out;

  u16* ws = (u16*)d_ws;
  u16* xb = ws;                  // 8192*1024
  u16* wqT = xb + 8388608;       // 3072*1024
  u16* woT = wqT + 3145728;      // 1024*1024
  u16* qb = woT + 1048576;       // 64*2048*64
  u16* kb = qb + 8388608;
  u16* vb = kb + 8388608;        // transposed [bh][64][2048]
  u16* ao = vb + 8388608;        // 8192*1024

  cvt_x<<<4096, 256, 0, stream>>>(x, xb, 8388608);
  transpose_cvt<<<dim3(96, 32), dim3(32, 8), 0, stream>>>(Wqkv, wqT, 1024, 3072);
  transpose_cvt<<<dim3(32, 32), dim3(32, 8), 0, stream>>>(Wout, woT, 1024, 1024);
  gemm_bf16<0><<<dim3(24, 64), 256, 0, stream>>>(xb, wqT, bqkv, qb, kb, vb,
                                                 nullptr, 3072, 1024);
  attn_kernel<<<dim3(16, 64), 256, 0, stream>>>(qb, kb, vb, ao);
  gemm_bf16<1><<<dim3(8, 64), 256, 0, stream>>>(ao, woT, bout, nullptr, nullptr,
                                                nullptr, out, 1024, 1024);
}

// Round 2
// 248.017 us; speedup vs baseline: 1.5382x; 1.5382x over previous
//
#include <hip/hip_runtime.h>

typedef unsigned short u16;
typedef unsigned int u32;
typedef u16 u16x4 __attribute__((ext_vector_type(4)));
typedef u16 u16x8 __attribute__((ext_vector_type(8)));
typedef u32 u32x2 __attribute__((ext_vector_type(2)));
typedef u32 u32x4 __attribute__((ext_vector_type(4)));
typedef __bf16 bf16x8 __attribute__((ext_vector_type(8)));
typedef float f32x4 __attribute__((ext_vector_type(4)));

__device__ __forceinline__ u16 f2bf(float f) {
  unsigned int u = __float_as_uint(f);
  u += 0x7fffu + ((u >> 16) & 1u);
  return (u16)(u >> 16);
}

__device__ __forceinline__ u32 pack2(float lo, float hi) {
  return (u32)f2bf(lo) | ((u32)f2bf(hi) << 16);
}

__device__ __forceinline__ f32x4 mfma16(bf16x8 a, bf16x8 b, f32x4 c) {
  return __builtin_amdgcn_mfma_f32_16x16x32_bf16(a, b, c, 0, 0, 0);
}

// ---------------- fp32 -> bf16 convert (x) ----------------
__global__ __launch_bounds__(256) void cvt_x(const float* __restrict__ in,
                                             u16* __restrict__ out, int n) {
  int i = (blockIdx.x * 256 + threadIdx.x) * 8;
  if (i >= n) return;
  u16x8 o;
#pragma unroll
  for (int j = 0; j < 8; j++) o[j] = f2bf(in[i + j]);
  *(u16x8*)&out[i] = o;
}

// ------------- transpose + convert: in [R][C] f32 -> out [C][R] bf16 -------------
__global__ __launch_bounds__(256) void transpose_cvt(const float* __restrict__ in,
                                                     u16* __restrict__ out,
                                                     int R, int C) {
  __shared__ float tile[32][33];
  int gx = blockIdx.x * 32, gy = blockIdx.y * 32;
  int tx = threadIdx.x, ty = threadIdx.y;
#pragma unroll
  for (int i = 0; i < 4; i++)
    tile[ty + i * 8][tx] = in[(size_t)(gy + ty + i * 8) * C + gx + tx];
  __syncthreads();
#pragma unroll
  for (int i = 0; i < 4; i++) {
    int c = ty + i * 8;
    out[(size_t)(gx + c) * R + gy + tx] = f2bf(tile[tx][c]);
  }
}

// ---------------- GEMM: C[M,N] = A[M,K] * Bt[N,K]^T  (bf16 in, fp32 acc) ----------
// EPI 0: QKV epilogue -> scatter to q (x 0.125*log2e), k, v^T buffers (bf16)
// EPI 1: fp32 out + bias
template <int EPI>
__global__ __launch_bounds__(256, 2) void gemm_bf16(
    const u16* __restrict__ A, const u16* __restrict__ Bt,
    const float* __restrict__ bias, u16* __restrict__ qb, u16* __restrict__ kb,
    u16* __restrict__ vb, float* __restrict__ fout, int N, int K) {
  __shared__ u16 As[128][40];
  __shared__ u16 Bs[128][40];
  const int tid = threadIdx.x;
  const int wave = tid >> 6;
  const int lane = tid & 63;
  const int wr = wave >> 1, wc = wave & 1;
  const int l15 = lane & 15, l4 = lane >> 4;
  const int bm = blockIdx.y * 128, bn = blockIdx.x * 128;
  const int srow = tid >> 2;
  const int scol = (tid & 3) * 8;

  const u16* Ap = A + (size_t)(bm + srow) * K + scol;
  const u16* Bp = Bt + (size_t)(bn + srow) * K + scol;
  const size_t rstep = (size_t)64 * K;

  f32x4 acc[4][4] = {};

  u16x8 ra0 = *(const u16x8*)(Ap);
  u16x8 ra1 = *(const u16x8*)(Ap + rstep);
  u16x8 rb0 = *(const u16x8*)(Bp);
  u16x8 rb1 = *(const u16x8*)(Bp + rstep);

  for (int k0 = 0; k0 < K; k0 += 32) {
    __syncthreads();
    *(u16x8*)&As[srow][scol] = ra0;
    *(u16x8*)&As[srow + 64][scol] = ra1;
    *(u16x8*)&Bs[srow][scol] = rb0;
    *(u16x8*)&Bs[srow + 64][scol] = rb1;
    __syncthreads();
    if (k0 + 32 < K) {
      ra0 = *(const u16x8*)(Ap + k0 + 32);
      ra1 = *(const u16x8*)(Ap + rstep + k0 + 32);
      rb0 = *(const u16x8*)(Bp + k0 + 32);
      rb1 = *(const u16x8*)(Bp + rstep + k0 + 32);
    }
    bf16x8 af[4], bfr[4];
#pragma unroll
    for (int mi = 0; mi < 4; mi++)
      af[mi] = *(const bf16x8*)&As[wr * 64 + mi * 16 + l15][l4 * 8];
#pragma unroll
    for (int ni = 0; ni < 4; ni++)
      bfr[ni] = *(const bf16x8*)&Bs[wc * 64 + ni * 16 + l15][l4 * 8];
#pragma unroll
    for (int mi = 0; mi < 4; mi++)
#pragma unroll
      for (int ni = 0; ni < 4; ni++)
        acc[mi][ni] = mfma16(af[mi], bfr[ni], acc[mi][ni]);
  }

#pragma unroll
  for (int mi = 0; mi < 4; mi++) {
#pragma unroll
    for (int ni = 0; ni < 4; ni++) {
      const int col = bn + wc * 64 + ni * 16 + l15;
      const float bv = bias[col];
      const int row0 = bm + wr * 64 + mi * 16 + l4 * 4;
      if (EPI == 0) {
        const int which = col >> 10;
        const int hc = col & 1023;
        const int h = hc >> 6, d = hc & 63;
#pragma unroll
        for (int r = 0; r < 4; r++) {
          const int row = row0 + r;
          const int b = row >> 11, t = row & 2047;
          const float v = acc[mi][ni][r] + bv;
          if (which == 0)
            // 0.125 (1/sqrt(64)) * log2(e): softmax done in exp2 domain
            qb[((size_t)(b * 16 + h) * 2048 + t) * 64 + d] = f2bf(v * 0.18033688f);
          else if (which == 1)
            kb[((size_t)(b * 16 + h) * 2048 + t) * 64 + d] = f2bf(v);
          else
            vb[((size_t)(b * 16 + h) * 64 + d) * 2048 + t] = f2bf(v);
        }
      } else {
#pragma unroll
        for (int r = 0; r < 4; r++)
          fout[(size_t)(row0 + r) * N + col] = acc[mi][ni][r] + bv;
      }
    }
  }
}

// ---------------- flash attention (swapped-operand, transposed O) ----------------
// Q,K: [64 bh][2048][64] bf16 (Q pre-scaled by 0.125*log2e); Vt: [64 bh][64][2048]
// O: [4 b][2048 t][1024] bf16
// S^T = mfma(K rows, Q rows): col=l15=q (lane-local softmax row), row=l4*4+r=k
// O^T = mfma(Vt rows, P rows): col=l15=q -> alpha/l rescale lane-local
__global__ __launch_bounds__(256, 4) void attn_kernel(const u16* __restrict__ Q,
                                                      const u16* __restrict__ Kg,
                                                      const u16* __restrict__ Vt,
                                                      u16* __restrict__ O) {
  __shared__ u16 Ks[64 * 72];
  __shared__ u16 Vs[64 * 72];
  __shared__ u32 Ps[4][32 * 36];  // per-wave P, row stride 36 u32 = 144B
  const int tid = threadIdx.x;
  const int wave = tid >> 6;
  const int lane = tid & 63;
  const int l15 = lane & 15, l4 = lane >> 4;
  const int qt = blockIdx.x;
  const int bh = blockIdx.y;

  // Q fragments straight from global (read once; no LDS staging)
  const u16* qg = Q + ((size_t)bh * 2048 + qt * 128 + wave * 32) * 64;
  bf16x8 qf[2][2];
#pragma unroll
  for (int mi = 0; mi < 2; mi++)
#pragma unroll
    for (int kg2 = 0; kg2 < 2; kg2++)
      qf[mi][kg2] = *(const bf16x8*)&qg[(mi * 16 + l15) * 64 + kg2 * 32 + l4 * 8];

  float mrow[2] = {-1e30f, -1e30f};
  float lrow[2] = {0.f, 0.f};
  f32x4 oacc[4][2] = {};  // [di][mi]: O^T tile, rows d, cols q

  const int sr = tid >> 2;
  const int sc = (tid & 3) * 16;
  const u16* kbase = Kg + (size_t)bh * 2048 * 64;
  const u16* vbase = Vt + (size_t)bh * 64 * 2048;

  for (int kt = 0; kt < 32; kt++) {
    __syncthreads();
    {
      u16x8 k0v = *(const u16x8*)(kbase + (size_t)(kt * 64 + sr) * 64 + sc);
      u16x8 k1v = *(const u16x8*)(kbase + (size_t)(kt * 64 + sr) * 64 + sc + 8);
      u16x8 v0v = *(const u16x8*)(vbase + (size_t)sr * 2048 + kt * 64 + sc);
      u16x8 v1v = *(const u16x8*)(vbase + (size_t)sr * 2048 + kt * 64 + sc + 8);
      *(u16x8*)&Ks[sr * 72 + sc] = k0v;
      *(u16x8*)&Ks[sr * 72 + sc + 8] = k1v;
      *(u16x8*)&Vs[sr * 72 + sc] = v0v;
      *(u16x8*)&Vs[sr * 72 + sc + 8] = v1v;
    }
    __syncthreads();

    // S^T[k][q]: sacc[mi(qtile)][ni(ktile)], per lane k = ni*16 + l4*4 + r
    f32x4 sacc[2][4] = {};
#pragma unroll
    for (int kg2 = 0; kg2 < 2; kg2++) {
#pragma unroll
      for (int ni = 0; ni < 4; ni++) {
        bf16x8 kf = *(const bf16x8*)&Ks[(ni * 16 + l15) * 72 + kg2 * 32 + l4 * 8];
#pragma unroll
        for (int mi = 0; mi < 2; mi++)
          sacc[mi][ni] = mfma16(kf, qf[mi][kg2], sacc[mi][ni]);
      }
    }

    // in-register online softmax: each lane owns q = mi*16+l15 (16 k-vals/lane,
    // full row across the 4 l4 lane-groups)
#pragma unroll
    for (int mi = 0; mi < 2; mi++) {
      float pm = sacc[mi][0][0];
#pragma unroll
      for (int ni = 0; ni < 4; ni++)
#pragma unroll
        for (int r = 0; r < 4; r++) pm = fmaxf(pm, sacc[mi][ni][r]);
      pm = fmaxf(pm, __shfl_xor(pm, 16));
      pm = fmaxf(pm, __shfl_xor(pm, 32));
      const float mnew = fmaxf(mrow[mi], pm);
      const float alpha = __builtin_amdgcn_exp2f(mrow[mi] - mnew);
      mrow[mi] = mnew;
      float rs = 0.f;
#pragma unroll
      for (int ni = 0; ni < 4; ni++)
#pragma unroll
        for (int r = 0; r < 4; r++) {
          const float p = __builtin_amdgcn_exp2f(sacc[mi][ni][r] - mnew);
          sacc[mi][ni][r] = p;
          rs += p;
        }
      rs += __shfl_xor(rs, 16);
      rs += __shfl_xor(rs, 32);
      lrow[mi] = lrow[mi] * alpha + rs;
      // pack P row q (k-contiguous quads) and store 8B per (mi,ni)
#pragma unroll
      for (int ni = 0; ni < 4; ni++) {
        u32x2 w;
        w[0] = pack2(sacc[mi][ni][0], sacc[mi][ni][1]);
        w[1] = pack2(sacc[mi][ni][2], sacc[mi][ni][3]);
        *(u32x2*)&Ps[wave][(mi * 16 + l15) * 36 + ni * 8 + l4 * 2] = w;
      }
      // rescale O^T columns (q = mi*16+l15: lane-local alpha)
#pragma unroll
      for (int di = 0; di < 4; di++) oacc[di][mi] *= alpha;
    }

    // same-wave LDS write->read: HW is in-order per wave; stop compiler reorder
    asm volatile("" ::: "memory");

    // O^T += Vt rows (A) x P rows (B); Ps is per-wave, no barrier needed
#pragma unroll
    for (int kg2 = 0; kg2 < 2; kg2++) {
      bf16x8 pf[2];
#pragma unroll
      for (int mi = 0; mi < 2; mi++) {
        u32x4 praw = *(const u32x4*)&Ps[wave][(mi * 16 + l15) * 36 + kg2 * 16 + l4 * 4];
        pf[mi] = __builtin_bit_cast(bf16x8, praw);
      }
#pragma unroll
      for (int di = 0; di < 4; di++) {
        bf16x8 vf = *(const bf16x8*)&Vs[(di * 16 + l15) * 72 + kg2 * 32 + l4 * 8];
#pragma unroll
        for (int mi = 0; mi < 2; mi++)
          oacc[di][mi] = mfma16(vf, pf[mi], oacc[di][mi]);
      }
    }
  }

  // epilogue: O^T rows d = di*16+l4*4+r, col q = mi*16+l15 (invl lane-local)
  const int b = bh >> 4, h = bh & 15;
#pragma unroll
  for (int mi = 0; mi < 2; mi++) {
    const float invl = 1.0f / lrow[mi];
    const int t = qt * 128 + wave * 32 + mi * 16 + l15;
#pragma unroll
    for (int di = 0; di < 4; di++) {
      u16x4 o;
#pragma unroll
      for (int r = 0; r < 4; r++) o[r] = f2bf(oacc[di][mi][r] * invl);
      *(u16x4*)&O[((size_t)b * 2048 + t) * 1024 + h * 64 + di * 16 + l4 * 4] = o;
    }
  }
}

extern "C" void kernel_launch(void* const* d_in, const int* in_sizes, int n_in,
                              void* d_out, int out_size, void* d_ws, size_t ws_size,
                              hipStream_t stream) {
  const float* x = (const float*)d_in[0];
  const float* Wqkv = (const float*)d_in[1];
  const float* bqkv = (const float*)d_in[2];
  const float* Wout = (const float*)d_in[3];
  const float* bout = (const float*)d_in[4];
  float* out = (float*)d_out;

  u16* ws = (u16*)d_ws;
  u16* xb = ws;                  // 8192*1024
  u16* wqT = xb + 8388608;       // 3072*1024
  u16* woT = wqT + 3145728;      // 1024*1024
  u16* qb = woT + 1048576;       // 64*2048*64
  u16* kb = qb + 8388608;
  u16* vb = kb + 8388608;        // transposed [bh][64][2048]
  u16* ao = vb + 8388608;        // 8192*1024

  cvt_x<<<4096, 256, 0, stream>>>(x, xb, 8388608);
  transpose_cvt<<<dim3(96, 32), dim3(32, 8), 0, stream>>>(Wqkv, wqT, 1024, 3072);
  transpose_cvt<<<dim3(32, 32), dim3(32, 8), 0, stream>>>(Wout, woT, 1024, 1024);
  gemm_bf16<0><<<dim3(24, 64), 256, 0, stream>>>(xb, wqT, bqkv, qb, kb, vb,
                                                 nullptr, 3072, 1024);
  attn_kernel<<<dim3(16, 64), 256, 0, stream>>>(qb, kb, vb, ao);
  gemm_bf16<1><<<dim3(8, 64), 256, 0, stream>>>(ao, woT, bout, nullptr, nullptr,
                                                nullptr, out, 1024, 1024);
}

// Round 3
// 242.175 us; speedup vs baseline: 1.5753x; 1.0241x over previous
//
#include <hip/hip_runtime.h>

typedef unsigned short u16;
typedef unsigned int u32;
typedef u16 u16x4 __attribute__((ext_vector_type(4)));
typedef u16 u16x8 __attribute__((ext_vector_type(8)));
typedef u32 u32x2 __attribute__((ext_vector_type(2)));
typedef u32 u32x4 __attribute__((ext_vector_type(4)));
typedef __bf16 bf16x2 __attribute__((ext_vector_type(2)));
typedef __bf16 bf16x8 __attribute__((ext_vector_type(8)));
typedef float f32x4 __attribute__((ext_vector_type(4)));

__device__ __forceinline__ u16 f2bf(float f) {
  return __builtin_bit_cast(u16, (__bf16)f);
}

__device__ __forceinline__ u32 packbf2(float lo, float hi) {
  bf16x2 t;
  t[0] = (__bf16)lo;
  t[1] = (__bf16)hi;
  return __builtin_bit_cast(u32, t);
}

__device__ __forceinline__ f32x4 mfma16(bf16x8 a, bf16x8 b, f32x4 c) {
  return __builtin_amdgcn_mfma_f32_16x16x32_bf16(a, b, c, 0, 0, 0);
}

#define GLOAD_LDS16(gsrc, ldst)                                              \
  __builtin_amdgcn_global_load_lds(                                          \
      (const __attribute__((address_space(1))) void*)(gsrc),                 \
      (__attribute__((address_space(3))) void*)(ldst), 16, 0, 0)

// ---------------- fp32 -> bf16 convert (x) ----------------
__global__ __launch_bounds__(256) void cvt_x(const float* __restrict__ in,
                                             u16* __restrict__ out, int n) {
  int i = (blockIdx.x * 256 + threadIdx.x) * 8;
  if (i >= n) return;
  u16x8 o;
#pragma unroll
  for (int j = 0; j < 8; j++) o[j] = f2bf(in[i + j]);
  *(u16x8*)&out[i] = o;
}

// ------------- transpose + convert: in [R][C] f32 -> out [C][R] bf16 -------------
__global__ __launch_bounds__(256) void transpose_cvt(const float* __restrict__ in,
                                                     u16* __restrict__ out,
                                                     int R, int C) {
  __shared__ float tile[32][33];
  int gx = blockIdx.x * 32, gy = blockIdx.y * 32;
  int tx = threadIdx.x, ty = threadIdx.y;
#pragma unroll
  for (int i = 0; i < 4; i++)
    tile[ty + i * 8][tx] = in[(size_t)(gy + ty + i * 8) * C + gx + tx];
  __syncthreads();
#pragma unroll
  for (int i = 0; i < 4; i++) {
    int c = ty + i * 8;
    out[(size_t)(gx + c) * R + gy + tx] = f2bf(tile[tx][c]);
  }
}

// ---------------- GEMM: C[M,N] = A[M,K] * Bt[N,K]^T  (bf16 in, fp32 acc) ----------
// m97 structure: BK=64, global_load_lds width-16, XOR-swizzled LDS (chunk^=row&7).
// EPI 0: QKV epilogue -> scatter to q (x 0.125*log2e), k, v^T buffers (bf16)
// EPI 1: fp32 out + bias
template <int EPI>
__global__ __launch_bounds__(256, 3) void gemm_bf16(
    const u16* __restrict__ A, const u16* __restrict__ Bt,
    const float* __restrict__ bias, u16* __restrict__ qb, u16* __restrict__ kb,
    u16* __restrict__ vb, float* __restrict__ fout, int N, int K) {
  __shared__ u16 As[128 * 64];  // [row][64] logical; chunk c at c^(row&7)
  __shared__ u16 Bs[128 * 64];
  const int tid = threadIdx.x;
  const int wave = tid >> 6;
  const int lane = tid & 63;
  const int wr = wave >> 1, wc = wave & 1;
  const int l15 = lane & 15, l4 = lane >> 4;
  const int bm = blockIdx.y * 128, bn = blockIdx.x * 128;

  // staging: call c covers rows c*32 + wave*8 + lane/8, chunk (lane&7)^(row&7)
  const int srow = wave * 8 + (lane >> 3);
  const int slch = lane & 7;
  const int ldst = wave * 512;  // u16 offset within a 2048-u16 call region

  f32x4 acc[4][4] = {};

  for (int k0 = 0; k0 < K; k0 += 64) {
    __syncthreads();
#pragma unroll
    for (int c = 0; c < 4; c++) {
      const int row = c * 32 + srow;
      const int sch = slch ^ (row & 7);
      GLOAD_LDS16(A + (size_t)(bm + row) * K + k0 + sch * 8,
                  As + c * 2048 + ldst);
      GLOAD_LDS16(Bt + (size_t)(bn + row) * K + k0 + sch * 8,
                  Bs + c * 2048 + ldst);
    }
    __syncthreads();

    bf16x8 af[4][2], bfr[4][2];
#pragma unroll
    for (int mi = 0; mi < 4; mi++) {
      const int row = wr * 64 + mi * 16 + l15;
#pragma unroll
      for (int kg = 0; kg < 2; kg++)
        af[mi][kg] = *(const bf16x8*)&As[row * 64 + (((kg * 4 + l4) ^ (row & 7)) * 8)];
    }
#pragma unroll
    for (int ni = 0; ni < 4; ni++) {
      const int row = wc * 64 + ni * 16 + l15;
#pragma unroll
      for (int kg = 0; kg < 2; kg++)
        bfr[ni][kg] = *(const bf16x8*)&Bs[row * 64 + (((kg * 4 + l4) ^ (row & 7)) * 8)];
    }
#pragma unroll
    for (int kg = 0; kg < 2; kg++)
#pragma unroll
      for (int mi = 0; mi < 4; mi++)
#pragma unroll
        for (int ni = 0; ni < 4; ni++)
          acc[mi][ni] = mfma16(af[mi][kg], bfr[ni][kg], acc[mi][ni]);
  }

#pragma unroll
  for (int mi = 0; mi < 4; mi++) {
#pragma unroll
    for (int ni = 0; ni < 4; ni++) {
      const int col = bn + wc * 64 + ni * 16 + l15;
      const float bv = bias[col];
      const int row0 = bm + wr * 64 + mi * 16 + l4 * 4;
      if (EPI == 0) {
        const int which = col >> 10;
        const int hc = col & 1023;
        const int h = hc >> 6, d = hc & 63;
#pragma unroll
        for (int r = 0; r < 4; r++) {
          const int row = row0 + r;
          const int b = row >> 11, t = row & 2047;
          const float v = acc[mi][ni][r] + bv;
          if (which == 0)
            // 0.125 (1/sqrt(64)) * log2(e): softmax done in exp2 domain
            qb[((size_t)(b * 16 + h) * 2048 + t) * 64 + d] = f2bf(v * 0.18033688f);
          else if (which == 1)
            kb[((size_t)(b * 16 + h) * 2048 + t) * 64 + d] = f2bf(v);
          else
            vb[((size_t)(b * 16 + h) * 64 + d) * 2048 + t] = f2bf(v);
        }
      } else {
#pragma unroll
        for (int r = 0; r < 4; r++)
          fout[(size_t)(row0 + r) * N + col] = acc[mi][ni][r] + bv;
      }
    }
  }
}

// ---------------- flash attention (swapped-operand, transposed O) ----------------
// Q,K: [64 bh][2048][64] bf16 (Q pre-scaled by 0.125*log2e); Vt: [64 bh][64][2048]
// O: [4 b][2048 t][1024] bf16
// S^T = mfma(K rows, Q rows): col=l15=q (lane-local softmax row)
// O^T = mfma(Vt rows, P rows): col=l15=q -> alpha/l rescale lane-local
// All LDS tiles [*][128B] with chunk^=(row&7) swizzle -> 2 lanes/bank (free).
__global__ __launch_bounds__(256, 4) void attn_kernel(const u16* __restrict__ Q,
                                                      const u16* __restrict__ Kg,
                                                      const u16* __restrict__ Vt,
                                                      u16* __restrict__ O) {
  __shared__ u16 Ks[64 * 64];
  __shared__ u16 Vs[64 * 64];
  __shared__ u32 Ps[4][32 * 32];  // per-wave P^T, 32 rows x 128B
  const int tid = threadIdx.x;
  const int wave = tid >> 6;
  const int lane = tid & 63;
  const int l15 = lane & 15, l4 = lane >> 4;
  const int qt = blockIdx.x;
  const int bh = blockIdx.y;

  // Q fragments straight from global (read once; no LDS staging)
  const u16* qg = Q + ((size_t)bh * 2048 + qt * 128 + wave * 32) * 64;
  bf16x8 qf[2][2];
#pragma unroll
  for (int mi = 0; mi < 2; mi++)
#pragma unroll
    for (int kg2 = 0; kg2 < 2; kg2++)
      qf[mi][kg2] = *(const bf16x8*)&qg[(mi * 16 + l15) * 64 + kg2 * 32 + l4 * 8];

  float mrow[2] = {-1e30f, -1e30f};
  float lrow[2] = {0.f, 0.f};
  f32x4 oacc[4][2] = {};  // [di][mi]: O^T tile, rows d, cols q

  const int srow = wave * 8 + (lane >> 3);  // + c*32
  const int slch = lane & 7;
  const int ldst = wave * 512;
  const u16* kbase = Kg + (size_t)bh * 2048 * 64;
  const u16* vbase = Vt + (size_t)bh * 64 * 2048;
  u32* const pw = &Ps[wave][0];

  for (int kt = 0; kt < 32; kt++) {
    __syncthreads();
#pragma unroll
    for (int c = 0; c < 2; c++) {
      const int row = c * 32 + srow;
      const int sch = slch ^ (row & 7);
      GLOAD_LDS16(kbase + (size_t)(kt * 64 + row) * 64 + sch * 8,
                  Ks + c * 2048 + ldst);
      GLOAD_LDS16(vbase + (size_t)row * 2048 + kt * 64 + sch * 8,
                  Vs + c * 2048 + ldst);
    }
    __syncthreads();

    // S^T[k][q]: sacc[mi(qtile)][ni(ktile)], per lane k = ni*16 + l4*4 + r
    f32x4 sacc[2][4] = {};
#pragma unroll
    for (int kg2 = 0; kg2 < 2; kg2++) {
#pragma unroll
      for (int ni = 0; ni < 4; ni++) {
        const int row = ni * 16 + l15;
        bf16x8 kf =
            *(const bf16x8*)&Ks[row * 64 + (((kg2 * 4 + l4) ^ (row & 7)) * 8)];
#pragma unroll
        for (int mi = 0; mi < 2; mi++)
          sacc[mi][ni] = mfma16(kf, qf[mi][kg2], sacc[mi][ni]);
      }
    }

    // in-register online softmax: lane owns q = mi*16+l15 (16 k-vals/lane;
    // full row = 4 l4 lane-groups -> 2 cross-lane reduce steps)
#pragma unroll
    for (int mi = 0; mi < 2; mi++) {
      float pm0 = fmaxf(fmaxf(sacc[mi][0][0], sacc[mi][0][1]),
                        fmaxf(sacc[mi][0][2], sacc[mi][0][3]));
      float pm1 = fmaxf(fmaxf(sacc[mi][1][0], sacc[mi][1][1]),
                        fmaxf(sacc[mi][1][2], sacc[mi][1][3]));
      float pm2 = fmaxf(fmaxf(sacc[mi][2][0], sacc[mi][2][1]),
                        fmaxf(sacc[mi][2][2], sacc[mi][2][3]));
      float pm3 = fmaxf(fmaxf(sacc[mi][3][0], sacc[mi][3][1]),
                        fmaxf(sacc[mi][3][2], sacc[mi][3][3]));
      float pm = fmaxf(fmaxf(pm0, pm1), fmaxf(pm2, pm3));
      pm = fmaxf(pm, __shfl_xor(pm, 16));
      pm = fmaxf(pm, __shfl_xor(pm, 32));
      const float mnew = fmaxf(mrow[mi], pm);
      const float alpha = __builtin_amdgcn_exp2f(mrow[mi] - mnew);
      mrow[mi] = mnew;
      float rs = 0.f;
#pragma unroll
      for (int ni = 0; ni < 4; ni++)
#pragma unroll
        for (int r = 0; r < 4; r++) {
          const float p = __builtin_amdgcn_exp2f(sacc[mi][ni][r] - mnew);
          sacc[mi][ni][r] = p;
          rs += p;
        }
      rs += __shfl_xor(rs, 16);
      rs += __shfl_xor(rs, 32);
      lrow[mi] = lrow[mi] * alpha + rs;
      // pack P row q (k-contiguous pairs) -> swizzled per-wave LDS, 8B stores
      const int row = mi * 16 + l15;
#pragma unroll
      for (int ni = 0; ni < 4; ni++) {
        u32x2 w;
        w[0] = packbf2(sacc[mi][ni][0], sacc[mi][ni][1]);
        w[1] = packbf2(sacc[mi][ni][2], sacc[mi][ni][3]);
        const int boff = (ni * 32 + l4 * 8) ^ ((row & 7) << 4);
        *(u32x2*)((char*)pw + row * 128 + boff) = w;
      }
      // rescale O^T columns (q = mi*16+l15: lane-local alpha)
#pragma unroll
      for (int di = 0; di < 4; di++) oacc[di][mi] *= alpha;
    }

    // same-wave LDS write->read; stop compiler reorder
    asm volatile("" ::: "memory");

    // O^T += Vt rows (A) x P rows (B); Ps is per-wave, no barrier needed
#pragma unroll
    for (int kg2 = 0; kg2 < 2; kg2++) {
      bf16x8 pf[2];
#pragma unroll
      for (int mi = 0; mi < 2; mi++) {
        const int row = mi * 16 + l15;
        const int boff = (kg2 * 64 + l4 * 16) ^ ((row & 7) << 4);
        u32x4 praw = *(const u32x4*)((const char*)pw + row * 128 + boff);
        pf[mi] = __builtin_bit_cast(bf16x8, praw);
      }
#pragma unroll
      for (int di = 0; di < 4; di++) {
        const int row = di * 16 + l15;
        bf16x8 vf =
            *(const bf16x8*)&Vs[row * 64 + (((kg2 * 4 + l4) ^ (row & 7)) * 8)];
#pragma unroll
        for (int mi = 0; mi < 2; mi++)
          oacc[di][mi] = mfma16(vf, pf[mi], oacc[di][mi]);
      }
    }
  }

  // epilogue: O^T rows d = di*16+l4*4+r, col q = mi*16+l15 (invl lane-local)
  const int b = bh >> 4, h = bh & 15;
#pragma unroll
  for (int mi = 0; mi < 2; mi++) {
    const float invl = 1.0f / lrow[mi];
    const int t = qt * 128 + wave * 32 + mi * 16 + l15;
#pragma unroll
    for (int di = 0; di < 4; di++) {
      u16x4 o;
#pragma unroll
      for (int r = 0; r < 4; r++) o[r] = f2bf(oacc[di][mi][r] * invl);
      *(u16x4*)&O[((size_t)b * 2048 + t) * 1024 + h * 64 + di * 16 + l4 * 4] = o;
    }
  }
}

extern "C" void kernel_launch(void* const* d_in, const int* in_sizes, int n_in,
                              void* d_out, int out_size, void* d_ws, size_t ws_size,
                              hipStream_t stream) {
  const float* x = (const float*)d_in[0];
  const float* Wqkv = (const float*)d_in[1];
  const float* bqkv = (const float*)d_in[2];
  const float* Wout = (const float*)d_in[3];
  const float* bout = (const float*)d_in[4];
  float* out = (float*)d_out;

  u16* ws = (u16*)d_ws;
  u16* xb = ws;                  // 8192*1024
  u16* wqT = xb + 8388608;       // 3072*1024
  u16* woT = wqT + 3145728;      // 1024*1024
  u16* qb = woT + 1048576;       // 64*2048*64
  u16* kb = qb + 8388608;
  u16* vb = kb + 8388608;        // transposed [bh][64][2048]
  u16* ao = vb + 8388608;        // 8192*1024

  cvt_x<<<4096, 256, 0, stream>>>(x, xb, 8388608);
  transpose_cvt<<<dim3(96, 32), dim3(32, 8), 0, stream>>>(Wqkv, wqT, 1024, 3072);
  transpose_cvt<<<dim3(32, 32), dim3(32, 8), 0, stream>>>(Wout, woT, 1024, 1024);
  gemm_bf16<0><<<dim3(24, 64), 256, 0, stream>>>(xb, wqT, bqkv, qb, kb, vb,
                                                 nullptr, 3072, 1024);
  attn_kernel<<<dim3(16, 64), 256, 0, stream>>>(qb, kb, vb, ao);
  gemm_bf16<1><<<dim3(8, 64), 256, 0, stream>>>(ao, woT, bout, nullptr, nullptr,
                                                nullptr, out, 1024, 1024);
}

// Round 4
// 237.053 us; speedup vs baseline: 1.6093x; 1.0216x over previous
//
#include <hip/hip_runtime.h>

typedef unsigned short u16;
typedef unsigned int u32;
typedef u16 u16x4 __attribute__((ext_vector_type(4)));
typedef u16 u16x8 __attribute__((ext_vector_type(8)));
typedef u32 u32x2 __attribute__((ext_vector_type(2)));
typedef u32 u32x4 __attribute__((ext_vector_type(4)));
typedef __bf16 bf16x2 __attribute__((ext_vector_type(2)));
typedef __bf16 bf16x8 __attribute__((ext_vector_type(8)));
typedef float f32x4 __attribute__((ext_vector_type(4)));

__device__ __forceinline__ u16 f2bf(float f) {
  return __builtin_bit_cast(u16, (__bf16)f);
}

__device__ __forceinline__ u32 packbf2(float lo, float hi) {
  bf16x2 t;
  t[0] = (__bf16)lo;
  t[1] = (__bf16)hi;
  return __builtin_bit_cast(u32, t);
}

__device__ __forceinline__ f32x4 mfma16(bf16x8 a, bf16x8 b, f32x4 c) {
  return __builtin_amdgcn_mfma_f32_16x16x32_bf16(a, b, c, 0, 0, 0);
}

#define GLOAD_LDS16(gsrc, ldst)                                              \
  __builtin_amdgcn_global_load_lds(                                          \
      (const __attribute__((address_space(1))) void*)(gsrc),                 \
      (__attribute__((address_space(3))) void*)(ldst), 16, 0, 0)

// ---------------- fp32 -> bf16 convert (x) ----------------
__global__ __launch_bounds__(256) void cvt_x(const float* __restrict__ in,
                                             u16* __restrict__ out, int n) {
  int i = (blockIdx.x * 256 + threadIdx.x) * 8;
  if (i >= n) return;
  u16x8 o;
#pragma unroll
  for (int j = 0; j < 8; j++) o[j] = f2bf(in[i + j]);
  *(u16x8*)&out[i] = o;
}

// ------------- transpose + convert: in [R][C] f32 -> out [C][R] bf16 -------------
__global__ __launch_bounds__(256) void transpose_cvt(const float* __restrict__ in,
                                                     u16* __restrict__ out,
                                                     int R, int C) {
  __shared__ float tile[32][33];
  int gx = blockIdx.x * 32, gy = blockIdx.y * 32;
  int tx = threadIdx.x, ty = threadIdx.y;
#pragma unroll
  for (int i = 0; i < 4; i++)
    tile[ty + i * 8][tx] = in[(size_t)(gy + ty + i * 8) * C + gx + tx];
  __syncthreads();
#pragma unroll
  for (int i = 0; i < 4; i++) {
    int c = ty + i * 8;
    out[(size_t)(gx + c) * R + gy + tx] = f2bf(tile[tx][c]);
  }
}

// ---------------- GEMM: C[M,N] = A[M,K] * Bt[N,K]^T  (bf16 in, fp32 acc) ----------
// BK=64, global_load_lds w16, XOR-swizzle (chunk^=row&7), double-buffered LDS,
// one barrier per K-step. XCD row-panel grouping. GX = gridDim.x (compile-time).
// EPI 0: QKV epilogue -> scatter to q (x 0.125*log2e), k, v^T buffers (bf16)
// EPI 1: fp32 out + bias
template <int EPI, int GX>
__global__ __launch_bounds__(256, 2) void gemm_bf16(
    const u16* __restrict__ A, const u16* __restrict__ Bt,
    const float* __restrict__ bias, u16* __restrict__ qb, u16* __restrict__ kb,
    u16* __restrict__ vb, float* __restrict__ fout, int N, int K) {
  __shared__ u16 As[2][128 * 64];  // [row][64] logical; chunk c at c^(row&7)
  __shared__ u16 Bs[2][128 * 64];
  const int tid = threadIdx.x;
  const int wave = tid >> 6;
  const int lane = tid & 63;
  const int wr = wave >> 1, wc = wave & 1;
  const int l15 = lane & 15, l4 = lane >> 4;

  // XCD grouping: 8 consecutive row-panels per XCD (A reused within one L2)
  const int id = blockIdx.y * GX + blockIdx.x;
  const int xcd = id & 7;
  const int j = id >> 3;
  const int bm = (xcd * 8 + j / GX) * 128;
  const int bn = (j % GX) * 128;

  // staging: call c covers rows c*32 + wave*8 + lane/8, chunk (lane&7)^(row&7)
  const int srow = wave * 8 + (lane >> 3);
  const int slch = lane & 7;
  const int ldst = wave * 512;  // u16 offset within a 2048-u16 call region

  const u16* Abase = A + (size_t)bm * K;
  const u16* Bbase = Bt + (size_t)bn * K;

  f32x4 acc[4][4] = {};

  auto STAGE = [&](int buf, int k0) {
#pragma unroll
    for (int c = 0; c < 4; c++) {
      const int row = c * 32 + srow;
      const int sch = slch ^ (row & 7);
      GLOAD_LDS16(Abase + (size_t)row * K + k0 + sch * 8,
                  &As[buf][c * 2048 + ldst]);
      GLOAD_LDS16(Bbase + (size_t)row * K + k0 + sch * 8,
                  &Bs[buf][c * 2048 + ldst]);
    }
  };

  STAGE(0, 0);
  int cur = 0;
  for (int k0 = 0; k0 < K; k0 += 64) {
    __syncthreads();  // drains vmcnt: buf[cur] ready (loads flew during compute)
    if (k0 + 64 < K) STAGE(cur ^ 1, k0 + 64);

    const u16* as = As[cur];
    const u16* bs = Bs[cur];
    bf16x8 af[4][2], bfr[4][2];
#pragma unroll
    for (int mi = 0; mi < 4; mi++) {
      const int row = wr * 64 + mi * 16 + l15;
#pragma unroll
      for (int kg = 0; kg < 2; kg++)
        af[mi][kg] = *(const bf16x8*)&as[row * 64 + (((kg * 4 + l4) ^ (row & 7)) * 8)];
    }
#pragma unroll
    for (int ni = 0; ni < 4; ni++) {
      const int row = wc * 64 + ni * 16 + l15;
#pragma unroll
      for (int kg = 0; kg < 2; kg++)
        bfr[ni][kg] = *(const bf16x8*)&bs[row * 64 + (((kg * 4 + l4) ^ (row & 7)) * 8)];
    }
#pragma unroll
    for (int kg = 0; kg < 2; kg++)
#pragma unroll
      for (int mi = 0; mi < 4; mi++)
#pragma unroll
        for (int ni = 0; ni < 4; ni++)
          acc[mi][ni] = mfma16(af[mi][kg], bfr[ni][kg], acc[mi][ni]);
    cur ^= 1;
  }

#pragma unroll
  for (int mi = 0; mi < 4; mi++) {
#pragma unroll
    for (int ni = 0; ni < 4; ni++) {
      const int col = bn + wc * 64 + ni * 16 + l15;
      const float bv = bias[col];
      const int row0 = bm + wr * 64 + mi * 16 + l4 * 4;
      if (EPI == 0) {
        const int which = col >> 10;
        const int hc = col & 1023;
        const int h = hc >> 6, d = hc & 63;
#pragma unroll
        for (int r = 0; r < 4; r++) {
          const int row = row0 + r;
          const int b = row >> 11, t = row & 2047;
          const float v = acc[mi][ni][r] + bv;
          if (which == 0)
            // 0.125 (1/sqrt(64)) * log2(e): softmax done in exp2 domain
            qb[((size_t)(b * 16 + h) * 2048 + t) * 64 + d] = f2bf(v * 0.18033688f);
          else if (which == 1)
            kb[((size_t)(b * 16 + h) * 2048 + t) * 64 + d] = f2bf(v);
          else
            vb[((size_t)(b * 16 + h) * 64 + d) * 2048 + t] = f2bf(v);
        }
      } else {
#pragma unroll
        for (int r = 0; r < 4; r++)
          fout[(size_t)(row0 + r) * N + col] = acc[mi][ni][r] + bv;
      }
    }
  }
}

// ---------------- flash attention (swapped-operand, transposed O) ----------------
// Q,K: [64 bh][2048][64] bf16 (Q pre-scaled by 0.125*log2e); Vt: [64 bh][64][2048]
// O: [4 b][2048 t][1024] bf16
// S^T = mfma(K rows, Q rows): col=l15=q (lane-local softmax row)
// O^T = mfma(Vt rows, P rows): col=l15=q -> alpha/l rescale lane-local
// Double-buffered K/V, one barrier per KV-tile; XCD-grouped bh (8 bh per XCD).
__global__ __launch_bounds__(256, 3) void attn_kernel(const u16* __restrict__ Q,
                                                      const u16* __restrict__ Kg,
                                                      const u16* __restrict__ Vt,
                                                      u16* __restrict__ O) {
  __shared__ u16 Ks[2][64 * 64];
  __shared__ u16 Vs[2][64 * 64];
  __shared__ u32 Ps[4][32 * 32];  // per-wave P^T, 32 rows x 128B, swizzled
  const int tid = threadIdx.x;
  const int wave = tid >> 6;
  const int lane = tid & 63;
  const int l15 = lane & 15, l4 = lane >> 4;

  // XCD grouping: 8 bh per XCD -> that bh's K/V lives in one XCD's L2
  const int id = blockIdx.y * 16 + blockIdx.x;
  const int xcd = id & 7;
  const int j = id >> 3;
  const int bh = xcd * 8 + (j >> 4);
  const int qt = j & 15;

  // Q fragments straight from global (read once; no LDS staging)
  const u16* qg = Q + ((size_t)bh * 2048 + qt * 128 + wave * 32) * 64;
  bf16x8 qf[2][2];
#pragma unroll
  for (int mi = 0; mi < 2; mi++)
#pragma unroll
    for (int kg2 = 0; kg2 < 2; kg2++)
      qf[mi][kg2] = *(const bf16x8*)&qg[(mi * 16 + l15) * 64 + kg2 * 32 + l4 * 8];

  float mrow[2] = {-1e30f, -1e30f};
  float lrow[2] = {0.f, 0.f};
  f32x4 oacc[4][2] = {};  // [di][mi]: O^T tile, rows d, cols q

  const int srow = wave * 8 + (lane >> 3);  // + c*32
  const int slch = lane & 7;
  const int ldst = wave * 512;
  const u16* kbase = Kg + (size_t)bh * 2048 * 64;
  const u16* vbase = Vt + (size_t)bh * 64 * 2048;
  u32* const pw = &Ps[wave][0];

  auto STAGE = [&](int buf, int kt) {
#pragma unroll
    for (int c = 0; c < 2; c++) {
      const int row = c * 32 + srow;
      const int sch = slch ^ (row & 7);
      GLOAD_LDS16(kbase + (size_t)(kt * 64 + row) * 64 + sch * 8,
                  &Ks[buf][c * 2048 + ldst]);
      GLOAD_LDS16(vbase + (size_t)row * 2048 + kt * 64 + sch * 8,
                  &Vs[buf][c * 2048 + ldst]);
    }
  };

  STAGE(0, 0);
  int cur = 0;
  for (int kt = 0; kt < 32; kt++) {
    __syncthreads();  // buf[cur] ready; next-tile loads flew during compute
    if (kt + 1 < 32) STAGE(cur ^ 1, kt + 1);
    const u16* ks = Ks[cur];
    const u16* vs = Vs[cur];

    // S^T[k][q]: sacc[mi(qtile)][ni(ktile)], per lane k = ni*16 + l4*4 + r
    f32x4 sacc[2][4] = {};
#pragma unroll
    for (int kg2 = 0; kg2 < 2; kg2++) {
#pragma unroll
      for (int ni = 0; ni < 4; ni++) {
        const int row = ni * 16 + l15;
        bf16x8 kf =
            *(const bf16x8*)&ks[row * 64 + (((kg2 * 4 + l4) ^ (row & 7)) * 8)];
#pragma unroll
        for (int mi = 0; mi < 2; mi++)
          sacc[mi][ni] = mfma16(kf, qf[mi][kg2], sacc[mi][ni]);
      }
    }

    // in-register online softmax; lane owns q = mi*16+l15
#pragma unroll
    for (int mi = 0; mi < 2; mi++) {
      float pm0 = fmaxf(fmaxf(sacc[mi][0][0], sacc[mi][0][1]),
                        fmaxf(sacc[mi][0][2], sacc[mi][0][3]));
      float pm1 = fmaxf(fmaxf(sacc[mi][1][0], sacc[mi][1][1]),
                        fmaxf(sacc[mi][1][2], sacc[mi][1][3]));
      float pm2 = fmaxf(fmaxf(sacc[mi][2][0], sacc[mi][2][1]),
                        fmaxf(sacc[mi][2][2], sacc[mi][2][3]));
      float pm3 = fmaxf(fmaxf(sacc[mi][3][0], sacc[mi][3][1]),
                        fmaxf(sacc[mi][3][2], sacc[mi][3][3]));
      float pm = fmaxf(fmaxf(pm0, pm1), fmaxf(pm2, pm3));
      pm = fmaxf(pm, __shfl_xor(pm, 16));
      pm = fmaxf(pm, __shfl_xor(pm, 32));
      // defer-max (T13): skip rescale when no row grew past THR (exp2 domain)
      const bool noskip = !__all(pm - mrow[mi] <= 6.0f);
      float mnew = mrow[mi];
      if (noskip) {
        mnew = fmaxf(mrow[mi], pm);
        const float alpha = __builtin_amdgcn_exp2f(mrow[mi] - mnew);
        mrow[mi] = mnew;
        lrow[mi] *= alpha;
#pragma unroll
        for (int di = 0; di < 4; di++) oacc[di][mi] *= alpha;
      }
      float rs = 0.f;
#pragma unroll
      for (int ni = 0; ni < 4; ni++)
#pragma unroll
        for (int r = 0; r < 4; r++) {
          const float p = __builtin_amdgcn_exp2f(sacc[mi][ni][r] - mnew);
          sacc[mi][ni][r] = p;
          rs += p;
        }
      rs += __shfl_xor(rs, 16);
      rs += __shfl_xor(rs, 32);
      lrow[mi] += rs;
      // pack P row q (k-contiguous pairs) -> swizzled per-wave LDS, 8B stores
      const int row = mi * 16 + l15;
#pragma unroll
      for (int ni = 0; ni < 4; ni++) {
        u32x2 w;
        w[0] = packbf2(sacc[mi][ni][0], sacc[mi][ni][1]);
        w[1] = packbf2(sacc[mi][ni][2], sacc[mi][ni][3]);
        const int boff = (ni * 32 + l4 * 8) ^ ((row & 7) << 4);
        *(u32x2*)((char*)pw + row * 128 + boff) = w;
      }
    }

    // same-wave LDS write->read; stop compiler reorder
    asm volatile("" ::: "memory");

    // O^T += Vt rows (A) x P rows (B); Ps is per-wave, no barrier needed
#pragma unroll
    for (int kg2 = 0; kg2 < 2; kg2++) {
      bf16x8 pf[2];
#pragma unroll
      for (int mi = 0; mi < 2; mi++) {
        const int row = mi * 16 + l15;
        const int boff = (kg2 * 64 + l4 * 16) ^ ((row & 7) << 4);
        u32x4 praw = *(const u32x4*)((const char*)pw + row * 128 + boff);
        pf[mi] = __builtin_bit_cast(bf16x8, praw);
      }
#pragma unroll
      for (int di = 0; di < 4; di++) {
        const int row = di * 16 + l15;
        bf16x8 vf =
            *(const bf16x8*)&vs[row * 64 + (((kg2 * 4 + l4) ^ (row & 7)) * 8)];
#pragma unroll
        for (int mi = 0; mi < 2; mi++)
          oacc[di][mi] = mfma16(vf, pf[mi], oacc[di][mi]);
      }
    }
    cur ^= 1;
  }

  // epilogue: O^T rows d = di*16+l4*4+r, col q = mi*16+l15 (invl lane-local)
  const int b = bh >> 4, h = bh & 15;
#pragma unroll
  for (int mi = 0; mi < 2; mi++) {
    const float invl = 1.0f / lrow[mi];
    const int t = qt * 128 + wave * 32 + mi * 16 + l15;
#pragma unroll
    for (int di = 0; di < 4; di++) {
      u16x4 o;
#pragma unroll
      for (int r = 0; r < 4; r++) o[r] = f2bf(oacc[di][mi][r] * invl);
      *(u16x4*)&O[((size_t)b * 2048 + t) * 1024 + h * 64 + di * 16 + l4 * 4] = o;
    }
  }
}

extern "C" void kernel_launch(void* const* d_in, const int* in_sizes, int n_in,
                              void* d_out, int out_size, void* d_ws, size_t ws_size,
                              hipStream_t stream) {
  const float* x = (const float*)d_in[0];
  const float* Wqkv = (const float*)d_in[1];
  const float* bqkv = (const float*)d_in[2];
  const float* Wout = (const float*)d_in[3];
  const float* bout = (const float*)d_in[4];
  float* out = (float*)d_out;

  u16* ws = (u16*)d_ws;
  u16* xb = ws;                  // 8192*1024
  u16* wqT = xb + 8388608;       // 3072*1024
  u16* woT = wqT + 3145728;      // 1024*1024
  u16* qb = woT + 1048576;       // 64*2048*64
  u16* kb = qb + 8388608;
  u16* vb = kb + 8388608;        // transposed [bh][64][2048]
  u16* ao = vb + 8388608;        // 8192*1024

  cvt_x<<<4096, 256, 0, stream>>>(x, xb, 8388608);
  transpose_cvt<<<dim3(96, 32), dim3(32, 8), 0, stream>>>(Wqkv, wqT, 1024, 3072);
  transpose_cvt<<<dim3(32, 32), dim3(32, 8), 0, stream>>>(Wout, woT, 1024, 1024);
  gemm_bf16<0, 24><<<dim3(24, 64), 256, 0, stream>>>(xb, wqT, bqkv, qb, kb, vb,
                                                     nullptr, 3072, 1024);
  attn_kernel<<<dim3(16, 64), 256, 0, stream>>>(qb, kb, vb, ao);
  gemm_bf16<1, 8><<<dim3(8, 64), 256, 0, stream>>>(ao, woT, bout, nullptr,
                                                   nullptr, nullptr, out, 1024, 1024);
}

// Round 5
// 218.645 us; speedup vs baseline: 1.7448x; 1.0842x over previous
//
#include <hip/hip_runtime.h>

typedef unsigned short u16;
typedef unsigned int u32;
typedef u16 u16x4 __attribute__((ext_vector_type(4)));
typedef u16 u16x8 __attribute__((ext_vector_type(8)));
typedef u32 u32x2 __attribute__((ext_vector_type(2)));
typedef u32 u32x4 __attribute__((ext_vector_type(4)));
typedef __bf16 bf16x2 __attribute__((ext_vector_type(2)));
typedef __bf16 bf16x8 __attribute__((ext_vector_type(8)));
typedef float f32x4 __attribute__((ext_vector_type(4)));

__device__ __forceinline__ u16 f2bf(float f) {
  return __builtin_bit_cast(u16, (__bf16)f);
}

__device__ __forceinline__ u32 packbf2(float lo, float hi) {
  bf16x2 t;
  t[0] = (__bf16)lo;
  t[1] = (__bf16)hi;
  return __builtin_bit_cast(u32, t);
}

__device__ __forceinline__ f32x4 mfma16(bf16x8 a, bf16x8 b, f32x4 c) {
  return __builtin_amdgcn_mfma_f32_16x16x32_bf16(a, b, c, 0, 0, 0);
}

#define GLOAD_LDS16(gsrc, ldst)                                              \
  __builtin_amdgcn_global_load_lds(                                          \
      (const __attribute__((address_space(1))) void*)(gsrc),                 \
      (__attribute__((address_space(3))) void*)(ldst), 16, 0, 0)

// ---------------- fp32 -> bf16 convert (x) ----------------
__global__ __launch_bounds__(256) void cvt_x(const float* __restrict__ in,
                                             u16* __restrict__ out, int n) {
  int i = (blockIdx.x * 256 + threadIdx.x) * 8;
  if (i >= n) return;
  u16x8 o;
#pragma unroll
  for (int j = 0; j < 8; j++) o[j] = f2bf(in[i + j]);
  *(u16x8*)&out[i] = o;
}

// ------------- transpose + convert: in [R][C] f32 -> out [C][R] bf16 -------------
__global__ __launch_bounds__(256) void transpose_cvt(const float* __restrict__ in,
                                                     u16* __restrict__ out,
                                                     int R, int C) {
  __shared__ float tile[32][33];
  int gx = blockIdx.x * 32, gy = blockIdx.y * 32;
  int tx = threadIdx.x, ty = threadIdx.y;
#pragma unroll
  for (int i = 0; i < 4; i++)
    tile[ty + i * 8][tx] = in[(size_t)(gy + ty + i * 8) * C + gx + tx];
  __syncthreads();
#pragma unroll
  for (int i = 0; i < 4; i++) {
    int c = ty + i * 8;
    out[(size_t)(gx + c) * R + gy + tx] = f2bf(tile[tx][c]);
  }
}

// ---------------- GEMM: C[M,N] = A[M,K] * Bt[N,K]^T  (bf16 in, fp32 acc) ----------
// BK=64, global_load_lds w16, XOR-swizzle (chunk^=row&7), double-buffered LDS,
// one barrier per K-step. XCD row-panel grouping. GX = gridDim.x (compile-time).
// EPI 0: QKV epilogue -> scatter to q (x 0.125*log2e), k, v^T (k-PERMUTED) bufs
// EPI 1: fp32 out + bias
template <int EPI, int GX>
__global__ __launch_bounds__(256, 2) void gemm_bf16(
    const u16* __restrict__ A, const u16* __restrict__ Bt,
    const float* __restrict__ bias, u16* __restrict__ qb, u16* __restrict__ kb,
    u16* __restrict__ vb, float* __restrict__ fout, int N, int K) {
  __shared__ u16 As[2][128 * 64];  // [row][64] logical; chunk c at c^(row&7)
  __shared__ u16 Bs[2][128 * 64];
  const int tid = threadIdx.x;
  const int wave = tid >> 6;
  const int lane = tid & 63;
  const int wr = wave >> 1, wc = wave & 1;
  const int l15 = lane & 15, l4 = lane >> 4;

  // XCD grouping: 8 consecutive row-panels per XCD (A reused within one L2)
  const int id = blockIdx.y * GX + blockIdx.x;
  const int xcd = id & 7;
  const int j = id >> 3;
  const int bm = (xcd * 8 + j / GX) * 128;
  const int bn = (j % GX) * 128;

  // staging: call c covers rows c*32 + wave*8 + lane/8, chunk (lane&7)^(row&7)
  const int srow = wave * 8 + (lane >> 3);
  const int slch = lane & 7;
  const int ldst = wave * 512;  // u16 offset within a 2048-u16 call region

  const u16* Abase = A + (size_t)bm * K;
  const u16* Bbase = Bt + (size_t)bn * K;

  f32x4 acc[4][4] = {};

  auto STAGE = [&](int buf, int k0) {
#pragma unroll
    for (int c = 0; c < 4; c++) {
      const int row = c * 32 + srow;
      const int sch = slch ^ (row & 7);
      GLOAD_LDS16(Abase + (size_t)row * K + k0 + sch * 8,
                  &As[buf][c * 2048 + ldst]);
      GLOAD_LDS16(Bbase + (size_t)row * K + k0 + sch * 8,
                  &Bs[buf][c * 2048 + ldst]);
    }
  };

  STAGE(0, 0);
  int cur = 0;
  for (int k0 = 0; k0 < K; k0 += 64) {
    __syncthreads();  // drains vmcnt: buf[cur] ready (loads flew during compute)
    if (k0 + 64 < K) STAGE(cur ^ 1, k0 + 64);

    const u16* as = As[cur];
    const u16* bs = Bs[cur];
    bf16x8 af[4][2], bfr[4][2];
#pragma unroll
    for (int mi = 0; mi < 4; mi++) {
      const int row = wr * 64 + mi * 16 + l15;
#pragma unroll
      for (int kg = 0; kg < 2; kg++)
        af[mi][kg] = *(const bf16x8*)&as[row * 64 + (((kg * 4 + l4) ^ (row & 7)) * 8)];
    }
#pragma unroll
    for (int ni = 0; ni < 4; ni++) {
      const int row = wc * 64 + ni * 16 + l15;
#pragma unroll
      for (int kg = 0; kg < 2; kg++)
        bfr[ni][kg] = *(const bf16x8*)&bs[row * 64 + (((kg * 4 + l4) ^ (row & 7)) * 8)];
    }
    __builtin_amdgcn_s_setprio(1);
#pragma unroll
    for (int kg = 0; kg < 2; kg++)
#pragma unroll
      for (int mi = 0; mi < 4; mi++)
#pragma unroll
        for (int ni = 0; ni < 4; ni++)
          acc[mi][ni] = mfma16(af[mi][kg], bfr[ni][kg], acc[mi][ni]);
    __builtin_amdgcn_s_setprio(0);
    cur ^= 1;
  }

#pragma unroll
  for (int mi = 0; mi < 4; mi++) {
#pragma unroll
    for (int ni = 0; ni < 4; ni++) {
      const int col = bn + wc * 64 + ni * 16 + l15;
      const float bv = bias[col];
      const int row0 = bm + wr * 64 + mi * 16 + l4 * 4;
      if (EPI == 0) {
        const int which = col >> 10;
        const int hc = col & 1023;
        const int h = hc >> 6, d = hc & 63;
#pragma unroll
        for (int r = 0; r < 4; r++) {
          const int row = row0 + r;
          const int b = row >> 11, t = row & 2047;
          const float v = acc[mi][ni][r] + bv;
          if (which == 0)
            // 0.125 (1/sqrt(64)) * log2(e): softmax done in exp2 domain
            qb[((size_t)(b * 16 + h) * 2048 + t) * 64 + d] = f2bf(v * 0.18033688f);
          else if (which == 1)
            kb[((size_t)(b * 16 + h) * 2048 + t) * 64 + d] = f2bf(v);
          else {
            // k-permute within each 64-block so attn's PV B-frag is lane-local:
            // o=16n+4a+r  ->  o' = 32*(n>>1) + 8a + 4*(n&1) + r
            const int o = t & 63;
            const int op = (o & 3) | (((o >> 4) & 1) << 2) | (((o >> 2) & 3) << 3) |
                           ((o >> 5) << 5);
            const int tp = (t & ~63) | op;
            vb[((size_t)(b * 16 + h) * 64 + d) * 2048 + tp] = f2bf(v);
          }
        }
      } else {
#pragma unroll
        for (int r = 0; r < 4; r++)
          fout[(size_t)(row0 + r) * N + col] = acc[mi][ni][r] + bv;
      }
    }
  }
}

// ---------------- flash attention (swapped-operand, transposed O) ----------------
// Q,K: [64 bh][2048][64] bf16 (Q pre-scaled by 0.125*log2e)
// Vt: [64 bh][64][2048] bf16, k-axis PERMUTED within 64-blocks (see epilogue)
// O: [4 b][2048 t][1024] bf16
// S^T = mfma(K rows, Q rows): lane owns q=l15, k-quads ni*16+l4*4+r
// PV B-frag (k' = kg2*32+l4*8+j) == lane's own sacc quads {2kg2, 2kg2+1} via the
// V k-permutation -> P never leaves registers. O^T rescale lane-local.
__global__ __launch_bounds__(256, 4) void attn_kernel(const u16* __restrict__ Q,
                                                      const u16* __restrict__ Kg,
                                                      const u16* __restrict__ Vt,
                                                      u16* __restrict__ O) {
  __shared__ u16 Ks[2][64 * 64];
  __shared__ u16 Vs[2][64 * 64];
  const int tid = threadIdx.x;
  const int wave = tid >> 6;
  const int lane = tid & 63;
  const int l15 = lane & 15, l4 = lane >> 4;

  // XCD grouping: 8 bh per XCD -> that bh's K/V lives in one XCD's L2
  const int id = blockIdx.y * 16 + blockIdx.x;
  const int xcd = id & 7;
  const int j = id >> 3;
  const int bh = xcd * 8 + (j >> 4);
  const int qt = j & 15;

  // Q fragments straight from global (read once; no LDS staging)
  const u16* qg = Q + ((size_t)bh * 2048 + qt * 128 + wave * 32) * 64;
  bf16x8 qf[2][2];
#pragma unroll
  for (int mi = 0; mi < 2; mi++)
#pragma unroll
    for (int kg2 = 0; kg2 < 2; kg2++)
      qf[mi][kg2] = *(const bf16x8*)&qg[(mi * 16 + l15) * 64 + kg2 * 32 + l4 * 8];

  float mrow[2] = {-1e30f, -1e30f};
  float lrow[2] = {0.f, 0.f};
  f32x4 oacc[4][2] = {};  // [di][mi]: O^T tile, rows d, cols q

  const int srow = wave * 8 + (lane >> 3);  // + c*32
  const int slch = lane & 7;
  const int ldst = wave * 512;
  const u16* kbase = Kg + (size_t)bh * 2048 * 64;
  const u16* vbase = Vt + (size_t)bh * 64 * 2048;

  auto STAGE = [&](int buf, int kt) {
#pragma unroll
    for (int c = 0; c < 2; c++) {
      const int row = c * 32 + srow;
      const int sch = slch ^ (row & 7);
      GLOAD_LDS16(kbase + (size_t)(kt * 64 + row) * 64 + sch * 8,
                  &Ks[buf][c * 2048 + ldst]);
      GLOAD_LDS16(vbase + (size_t)row * 2048 + kt * 64 + sch * 8,
                  &Vs[buf][c * 2048 + ldst]);
    }
  };

  STAGE(0, 0);
  int cur = 0;
  for (int kt = 0; kt < 32; kt++) {
    __syncthreads();  // buf[cur] ready; next-tile loads flew during compute
    if (kt + 1 < 32) STAGE(cur ^ 1, kt + 1);
    const u16* ks = Ks[cur];
    const u16* vs = Vs[cur];

    // S^T[k][q]: sacc[mi(qtile)][ni(ktile)], per lane k = ni*16 + l4*4 + r
    f32x4 sacc[2][4] = {};
    __builtin_amdgcn_s_setprio(1);
#pragma unroll
    for (int kg2 = 0; kg2 < 2; kg2++) {
#pragma unroll
      for (int ni = 0; ni < 4; ni++) {
        const int row = ni * 16 + l15;
        bf16x8 kf =
            *(const bf16x8*)&ks[row * 64 + (((kg2 * 4 + l4) ^ (row & 7)) * 8)];
#pragma unroll
        for (int mi = 0; mi < 2; mi++)
          sacc[mi][ni] = mfma16(kf, qf[mi][kg2], sacc[mi][ni]);
      }
    }
    __builtin_amdgcn_s_setprio(0);

    // in-register online softmax; lane owns q = mi*16+l15
#pragma unroll
    for (int mi = 0; mi < 2; mi++) {
      float pm0 = fmaxf(fmaxf(sacc[mi][0][0], sacc[mi][0][1]),
                        fmaxf(sacc[mi][0][2], sacc[mi][0][3]));
      float pm1 = fmaxf(fmaxf(sacc[mi][1][0], sacc[mi][1][1]),
                        fmaxf(sacc[mi][1][2], sacc[mi][1][3]));
      float pm2 = fmaxf(fmaxf(sacc[mi][2][0], sacc[mi][2][1]),
                        fmaxf(sacc[mi][2][2], sacc[mi][2][3]));
      float pm3 = fmaxf(fmaxf(sacc[mi][3][0], sacc[mi][3][1]),
                        fmaxf(sacc[mi][3][2], sacc[mi][3][3]));
      float pm = fmaxf(fmaxf(pm0, pm1), fmaxf(pm2, pm3));
      pm = fmaxf(pm, __shfl_xor(pm, 16));
      pm = fmaxf(pm, __shfl_xor(pm, 32));
      // defer-max (T13): skip rescale when no row grew past THR (exp2 domain)
      const bool noskip = !__all(pm - mrow[mi] <= 6.0f);
      float mnew = mrow[mi];
      if (noskip) {
        mnew = fmaxf(mrow[mi], pm);
        const float alpha = __builtin_amdgcn_exp2f(mrow[mi] - mnew);
        mrow[mi] = mnew;
        lrow[mi] *= alpha;
#pragma unroll
        for (int di = 0; di < 4; di++) oacc[di][mi] *= alpha;
      }
      float rs = 0.f;
#pragma unroll
      for (int ni = 0; ni < 4; ni++)
#pragma unroll
        for (int r = 0; r < 4; r++) {
          const float p = __builtin_amdgcn_exp2f(sacc[mi][ni][r] - mnew);
          sacc[mi][ni][r] = p;
          rs += p;
        }
      rs += __shfl_xor(rs, 16);
      rs += __shfl_xor(rs, 32);
      lrow[mi] += rs;
    }

    // O^T += V(perm-k) rows (A) x P (B, in-register: own quads {2kg2,2kg2+1})
#pragma unroll
    for (int kg2 = 0; kg2 < 2; kg2++) {
      bf16x8 pf[2];
#pragma unroll
      for (int mi = 0; mi < 2; mi++) {
        u32x4 praw;
        praw[0] = packbf2(sacc[mi][2 * kg2][0], sacc[mi][2 * kg2][1]);
        praw[1] = packbf2(sacc[mi][2 * kg2][2], sacc[mi][2 * kg2][3]);
        praw[2] = packbf2(sacc[mi][2 * kg2 + 1][0], sacc[mi][2 * kg2 + 1][1]);
        praw[3] = packbf2(sacc[mi][2 * kg2 + 1][2], sacc[mi][2 * kg2 + 1][3]);
        pf[mi] = __builtin_bit_cast(bf16x8, praw);
      }
      __builtin_amdgcn_s_setprio(1);
#pragma unroll
      for (int di = 0; di < 4; di++) {
        const int row = di * 16 + l15;
        bf16x8 vf =
            *(const bf16x8*)&vs[row * 64 + (((kg2 * 4 + l4) ^ (row & 7)) * 8)];
#pragma unroll
        for (int mi = 0; mi < 2; mi++)
          oacc[di][mi] = mfma16(vf, pf[mi], oacc[di][mi]);
      }
      __builtin_amdgcn_s_setprio(0);
    }
    cur ^= 1;
  }

  // epilogue: O^T rows d = di*16+l4*4+r, col q = mi*16+l15 (invl lane-local)
  const int b = bh >> 4, h = bh & 15;
#pragma unroll
  for (int mi = 0; mi < 2; mi++) {
    const float invl = 1.0f / lrow[mi];
    const int t = qt * 128 + wave * 32 + mi * 16 + l15;
#pragma unroll
    for (int di = 0; di < 4; di++) {
      u16x4 o;
#pragma unroll
      for (int r = 0; r < 4; r++) o[r] = f2bf(oacc[di][mi][r] * invl);
      *(u16x4*)&O[((size_t)b * 2048 + t) * 1024 + h * 64 + di * 16 + l4 * 4] = o;
    }
  }
}

extern "C" void kernel_launch(void* const* d_in, const int* in_sizes, int n_in,
                              void* d_out, int out_size, void* d_ws, size_t ws_size,
                              hipStream_t stream) {
  const float* x = (const float*)d_in[0];
  const float* Wqkv = (const float*)d_in[1];
  const float* bqkv = (const float*)d_in[2];
  const float* Wout = (const float*)d_in[3];
  const float* bout = (const float*)d_in[4];
  float* out = (float*)d_out;

  u16* ws = (u16*)d_ws;
  u16* xb = ws;                  // 8192*1024
  u16* wqT = xb + 8388608;       // 3072*1024
  u16* woT = wqT + 3145728;      // 1024*1024
  u16* qb = woT + 1048576;       // 64*2048*64
  u16* kb = qb + 8388608;
  u16* vb = kb + 8388608;        // transposed [bh][64][2048], k-permuted
  u16* ao = vb + 8388608;        // 8192*1024

  cvt_x<<<4096, 256, 0, stream>>>(x, xb, 8388608);
  transpose_cvt<<<dim3(96, 32), dim3(32, 8), 0, stream>>>(Wqkv, wqT, 1024, 3072);
  transpose_cvt<<<dim3(32, 32), dim3(32, 8), 0, stream>>>(Wout, woT, 1024, 1024);
  gemm_bf16<0, 24><<<dim3(24, 64), 256, 0, stream>>>(xb, wqT, bqkv, qb, kb, vb,
                                                     nullptr, 3072, 1024);
  attn_kernel<<<dim3(16, 64), 256, 0, stream>>>(qb, kb, vb, ao);
  gemm_bf16<1, 8><<<dim3(8, 64), 256, 0, stream>>>(ao, woT, bout, nullptr,
                                                   nullptr, nullptr, out, 1024, 1024);
}